// Round 3
// baseline (219.360 us; speedup 1.0000x reference)
//
#include <hip/hip_runtime.h>

// ArtNetwork: y = sigmoid(Wout @ tanh(W8 @ ... tanh(W1 @ tanh(Win@x+b)) ...))
// Design:
//  - Hidden 16x16 layers via v_mfma_f32_16x16x16_f16 with A=W/4, B=h^T.
//    C/D layout (row=(lane>>4)*4+i, col=lane&15) == B layout (k=(lane>>4)*4+j,
//    n=lane&15), so MFMA out -> tanh -> next B frag. No LDS/shuffle.
//  - tanh via packed-f16 Pade(7,6): tanh(z) = zq*P(u)/Q(u), zq=z/4 (scale folded
//    into weights so MFMA emits zq), u=zq^2. |z|<=4 guaranteed (16 terms x 0.25 x 1),
//    Pade err <=1.5e-5 there; f16 eval err ~1e-3/layer. One shared v_rcp_f16 per
//    2 values via r=rcp(qa*qb). Cuts trans ops ~4x vs exp2-based tanh (T~10cyc each).
//  - sigmoid(z) = rcp(1+exp2(-log2(e)*z)), scale folded into Wout.
//  - 4096 blocks x 256 thr, launch_bounds(256,8): 32 waves/CU, 8 iters/wave, no tail.

typedef float  f32x4 __attribute__((ext_vector_type(4)));
typedef __fp16 f16x4 __attribute__((ext_vector_type(4)));
typedef __fp16 f16x2 __attribute__((ext_vector_type(2)));

#define KOUT (-1.4426950408889634f) // -log2(e)
#define QSC  0.25f                  // weight pre-scale so MFMA emits z/4

__device__ __forceinline__ f16x2 splat2(float v) {
    __fp16 h = (__fp16)v;
    f16x2 r = {h, h};
    return r;
}

// Packed tanh for 2 values. Input zq = z/4 (|zq|<=1). Pade(7,6) in u=zq^2:
// tanh(z) = zq * (4 + 8.205128u + 2.864339u^2 + 0.1212436u^3)
//              / (1 + 7.384615u + 5.967366u^2 + 0.8486901u^3)
__device__ __forceinline__ f16x2 pk_tanh(f16x2 zq) {
    const f16x2 C0 = splat2(4.0f);
    const f16x2 C1 = splat2(8.2051282f);
    const f16x2 C2 = splat2(2.8643390f);
    const f16x2 C3 = splat2(0.12124357f);
    const f16x2 D1 = splat2(7.3846154f);
    const f16x2 D2 = splat2(5.9673662f);
    const f16x2 D3 = splat2(0.84869012f);
    const f16x2 ONE = splat2(1.0f);

    f16x2 u = zq * zq;
    f16x2 p = C3 * u + C2;
    p = p * u + C1;
    p = p * u + C0;
    f16x2 q = D3 * u + D2;
    q = q * u + D1;
    q = q * u + ONE;
    f16x2 n = zq * p;
    // shared reciprocal: r = 1/(q.x*q.y); {1/q.x, 1/q.y} = r * {q.y, q.x}
    __fp16 qq = q.x * q.y;               // <= ~231, fine in f16
    __fp16 r  = __builtin_amdgcn_rcph(qq);
    f16x2 qs  = __builtin_shufflevector(q, q, 1, 0);
    f16x2 rr  = {r, r};
    f16x2 inv = rr * qs;
    return n * inv;
}

__global__ __launch_bounds__(256, 8)
void artnet_kernel(const float2* __restrict__ x,     // [N][2]
                   const float2* __restrict__ Win,   // [16][2]
                   const float*  __restrict__ bin,   // [16]
                   const float4* __restrict__ Wh,    // [8][16][16]
                   const float4* __restrict__ Wout,  // [3][16]
                   float* __restrict__ out,          // [N][3]
                   int nPairs, int nWaves)
{
    const int tid  = blockIdx.x * 256 + threadIdx.x;
    const int gw   = tid >> 6;            // global wave id
    const int lane = threadIdx.x & 63;
    const int row  = lane & 15;           // m / point-col index
    const int quad = lane >> 4;           // 0..3

    // ---- Preload hidden-layer A fragments: A[m=row][k=quad*4+j] = W[l][row][k]/4
    f16x4 aw[8];
#pragma unroll
    for (int l = 0; l < 8; ++l) {
        float4 w = Wh[l * 64 + row * 4 + quad];
        f16x2 lo = __builtin_amdgcn_cvt_pkrtz(w.x * QSC, w.y * QSC);
        f16x2 hi = __builtin_amdgcn_cvt_pkrtz(w.z * QSC, w.w * QSC);
        aw[l] = __builtin_shufflevector(lo, hi, 0, 1, 2, 3);
    }

    // ---- Input layer constants (features quad*4+j), pre-scaled by 1/4
    float wi0[4], wi1[4], bb[4];
#pragma unroll
    for (int j = 0; j < 4; ++j) {
        float2 wr = Win[quad * 4 + j];
        wi0[j] = wr.x * QSC;
        wi1[j] = wr.y * QSC;
        bb[j]  = bin[quad * 4 + j] * QSC;
    }

    // ---- Output layer constants, pre-scaled by -log2(e)
    float wo0[4], wo1[4], wo2[4];
    {
        float4 w0 = Wout[0 * 4 + quad];
        float4 w1 = Wout[1 * 4 + quad];
        float4 w2 = Wout[2 * 4 + quad];
        wo0[0] = w0.x * KOUT; wo0[1] = w0.y * KOUT; wo0[2] = w0.z * KOUT; wo0[3] = w0.w * KOUT;
        wo1[0] = w1.x * KOUT; wo1[1] = w1.y * KOUT; wo1[2] = w1.z * KOUT; wo1[3] = w1.w * KOUT;
        wo2[0] = w2.x * KOUT; wo2[1] = w2.y * KOUT; wo2[2] = w2.z * KOUT; wo2[3] = w2.w * KOUT;
    }

    const f32x4 zero4 = {0.0f, 0.0f, 0.0f, 0.0f};

    for (int pi = gw; pi < nPairs; pi += nWaves) {
        const int t0 = pi * 2;           // first tile of the pair
        f16x4 bf[2];
        f16x2 last01[2], last23[2];

        // ---- Input layer: zq = (x @ Win^T + b)/4 in f32, then packed tanh
#pragma unroll
        for (int s = 0; s < 2; ++s) {
            float2 xv = x[(t0 + s) * 16 + row];
            float h0 = __builtin_fmaf(xv.x, wi0[0], __builtin_fmaf(xv.y, wi1[0], bb[0]));
            float h1 = __builtin_fmaf(xv.x, wi0[1], __builtin_fmaf(xv.y, wi1[1], bb[1]));
            float h2 = __builtin_fmaf(xv.x, wi0[2], __builtin_fmaf(xv.y, wi1[2], bb[2]));
            float h3 = __builtin_fmaf(xv.x, wi0[3], __builtin_fmaf(xv.y, wi1[3], bb[3]));
            f16x2 t01 = pk_tanh(__builtin_amdgcn_cvt_pkrtz(h0, h1));
            f16x2 t23 = pk_tanh(__builtin_amdgcn_cvt_pkrtz(h2, h3));
            bf[s] = __builtin_shufflevector(t01, t23, 0, 1, 2, 3);
        }

        // ---- 8 hidden layers: MFMA (emits z/4) -> packed tanh -> next B frag
#pragma unroll
        for (int l = 0; l < 8; ++l) {
#pragma unroll
            for (int s = 0; s < 2; ++s) {
                f32x4 acc = __builtin_amdgcn_mfma_f32_16x16x16f16(aw[l], bf[s], zero4, 0, 0, 0);
                f16x2 t01 = pk_tanh(__builtin_amdgcn_cvt_pkrtz(acc[0], acc[1]));
                f16x2 t23 = pk_tanh(__builtin_amdgcn_cvt_pkrtz(acc[2], acc[3]));
                bf[s] = __builtin_shufflevector(t01, t23, 0, 1, 2, 3);
                if (l == 7) { last01[s] = t01; last23[s] = t23; }
            }
        }

        // ---- Output layer 16->3 + sigmoid. Cross-quad reduce via shfl_xor.
#pragma unroll
        for (int s = 0; s < 2; ++s) {
            float tl[4];
            tl[0] = (float)last01[s].x; tl[1] = (float)last01[s].y;
            tl[2] = (float)last23[s].x; tl[3] = (float)last23[s].y;
            float p0 = 0.0f, p1 = 0.0f, p2 = 0.0f;
#pragma unroll
            for (int j = 0; j < 4; ++j) {
                p0 = __builtin_fmaf(tl[j], wo0[j], p0);
                p1 = __builtin_fmaf(tl[j], wo1[j], p1);
                p2 = __builtin_fmaf(tl[j], wo2[j], p2);
            }
            p0 += __shfl_xor(p0, 16, 64); p0 += __shfl_xor(p0, 32, 64);
            p1 += __shfl_xor(p1, 16, 64); p1 += __shfl_xor(p1, 32, 64);
            p2 += __shfl_xor(p2, 16, 64); p2 += __shfl_xor(p2, 32, 64);
            // quad c (0..2) stores channel c of point (t0+s)*16+row
            float y  = (quad == 0) ? p0 : ((quad == 1) ? p1 : p2);
            float e  = __builtin_amdgcn_exp2f(y);
            float sg = __builtin_amdgcn_rcpf(e + 1.0f);
            if (quad < 3) {
                out[((t0 + s) * 16 + row) * 3 + quad] = sg;
            }
        }
    }
}

extern "C" void kernel_launch(void* const* d_in, const int* in_sizes, int n_in,
                              void* d_out, int out_size, void* d_ws, size_t ws_size,
                              hipStream_t stream) {
    const float2* x    = (const float2*)d_in[0];
    const float2* Win  = (const float2*)d_in[1];
    const float*  bin  = (const float*) d_in[2];
    const float4* Wh   = (const float4*)d_in[3];
    const float4* Wout = (const float4*)d_in[4];
    float* out = (float*)d_out;

    const int n      = in_sizes[0] / 2;   // 4,194,304 points
    const int nPairs = n / 32;            // 2 tiles of 16 points per wave-iter
    const int blocks = 4096;              // 16384 waves: 8 blocks/CU, 8 iters/wave
    const int nWaves = blocks * 4;

    artnet_kernel<<<blocks, 256, 0, stream>>>(x, Win, bin, Wh, Wout, out, nPairs, nWaves);
}